// Round 1
// 209.341 us; speedup vs baseline: 1.0508x; 1.0508x over previous
//
#include <hip/hip_runtime.h>
#include <hip/hip_fp16.h>
#include <math.h>

#define NN 50000
#define NE 800000
#define EPSV 1e-5f
#define BSHIFT 7
#define BSIZE 128
#define NB 391    // ceil(NN / 128)
#define CAP 2560  // slots per bucket

typedef _Float16 h2f   __attribute__((ext_vector_type(2)));
typedef _Float16 f16x8 __attribute__((ext_vector_type(8)));
typedef float    f32x4 __attribute__((ext_vector_type(4)));

// ---------------- weight prep (interleaved Wa/Wb + R cat), BN fold, cursor init ----------------
// Bcat layer0: K=96  rows: k<64 -> W0[(k&1)][k>>1][n] (interleave), k>=64 -> R0[k-64][n]
// Bcat layer1: K=192 rows: k<128 -> W1[(k&1)][k>>1][n],             k>=128 -> R1[k-128][n]
// bn[c]    = G*rsqrt(RV+eps)
// bn[64+c] = Bbias*bn[c] + BE - RM*bn[c]
__global__ __launch_bounds__(64) void prep_all_kernel(
        const float* __restrict__ W0, const float* __restrict__ R0,
        const float* __restrict__ W1, const float* __restrict__ R1,
        const float* __restrict__ W2, const float* __restrict__ R2,
        const float* __restrict__ B0, const float* __restrict__ B1,
        const float* __restrict__ G0, const float* __restrict__ BE0,
        const float* __restrict__ RM0, const float* __restrict__ RV0,
        const float* __restrict__ G1, const float* __restrict__ BE1,
        const float* __restrict__ RM1, const float* __restrict__ RV1,
        __half* __restrict__ Bf0, __half* __restrict__ Bf1, __half* __restrict__ Bf7,
        float* __restrict__ bn0, float* __restrict__ bn1,
        int* __restrict__ bcursor) {
    int lane = threadIdx.x;
    int bid = blockIdx.x;
    int c = lane & 15;
    int kbase = ((lane >> 4) << 3);
    _Float16 vals[8];
    if (bid < 12) {            // layer 0: ks=bid>>2 (0..2), nt=bid&3, K=96
        int ks = bid >> 2, nt = bid & 3;
        int n = nt * 16 + c;
#pragma unroll
        for (int j = 0; j < 8; ++j) {
            int kg = ks * 32 + kbase + j;
            float v = (kg < 64) ? W0[(kg & 1) * 2048 + (kg >> 1) * 64 + n]
                                : R0[(kg - 64) * 64 + n];
            vals[j] = (_Float16)v;
        }
        *reinterpret_cast<f16x8*>(Bf0 + ((size_t)(bid * 64 + lane)) * 8) =
            *reinterpret_cast<f16x8*>(vals);
    } else if (bid < 36) {     // layer 1: t=bid-12, ks=t>>2 (0..5), nt=t&3, K=192
        int t = bid - 12;
        int ks = t >> 2, nt = t & 3;
        int n = nt * 16 + c;
#pragma unroll
        for (int j = 0; j < 8; ++j) {
            int kg = ks * 32 + kbase + j;
            float v = (kg < 128) ? W1[(kg & 1) * 4096 + (kg >> 1) * 64 + n]
                                 : R1[(kg - 128) * 64 + n];
            vals[j] = (_Float16)v;
        }
        *reinterpret_cast<f16x8*>(Bf1 + ((size_t)(t * 64 + lane)) * 8) =
            *reinterpret_cast<f16x8*>(vals);
    } else if (bid < 40) {     // layer 2 (unchanged): [Wa|Wb packed, R], 2 ks x 2 nt
        int ksnt = bid - 36;   // 0..3
        int ks = ksnt >> 1, nt = ksnt & 1;
#pragma unroll
        for (int j = 0; j < 8; ++j) {
            int k = ks * 32 + kbase + j;
            float v = 0.f;
            if (nt == 0) {
                if (c < 7)                 v = W2[k * 7 + c];
                else if (c >= 8 && c < 15) v = W2[448 + k * 7 + (c - 8)];
            } else {
                if (c < 7)                 v = R2[k * 7 + c];
            }
            vals[j] = (_Float16)v;
        }
        *reinterpret_cast<f16x8*>(Bf7 + ((size_t)(ksnt * 64 + lane)) * 8) =
            *reinterpret_cast<f16x8*>(vals);
    } else if (bid == 40) {    // fold BN0
        float s = G0[lane] * rsqrtf(RV0[lane] + EPSV);
        bn0[lane] = s;
        bn0[64 + lane] = B0[lane] * s + BE0[lane] - RM0[lane] * s;
    } else if (bid == 41) {    // fold BN1
        float s = G1[lane] * rsqrtf(RV1[lane] + EPSV);
        bn1[lane] = s;
        bn1[64 + lane] = B1[lane] * s + BE1[lane] - RM1[lane] * s;
    } else {                   // bucket cursor init
        int b = (bid - 42) * 64 + lane;
        if (b < NB) bcursor[b] = b * CAP;
    }
}

// ---------------- fused: binB (blocks 0..NB-1) || x f32->f16 conversion ----------------
__global__ __launch_bounds__(256) void binB_xh_kernel(
        const int* __restrict__ src, const int* __restrict__ dst,
        const float* __restrict__ attr, int* __restrict__ bcursor,
        unsigned* __restrict__ es1su, unsigned char* __restrict__ es1dl, int E,
        const float* __restrict__ x, __half* __restrict__ xh) {
    __shared__ int hist[NB];
    __shared__ int base[NB];
    if (blockIdx.x >= NB) {    // x -> half, 8 floats/thread
        int t = (blockIdx.x - NB) * 256 + threadIdx.x;
        size_t idx = (size_t)t * 8;
        if (idx < (size_t)NN * 32) {
            float4 f0 = *reinterpret_cast<const float4*>(x + idx);
            float4 f1 = *reinterpret_cast<const float4*>(x + idx + 4);
            _Float16 v[8] = {(_Float16)f0.x, (_Float16)f0.y, (_Float16)f0.z, (_Float16)f0.w,
                             (_Float16)f1.x, (_Float16)f1.y, (_Float16)f1.z, (_Float16)f1.w};
            *reinterpret_cast<f16x8*>(xh + idx) = *reinterpret_cast<f16x8*>(v);
        }
        return;
    }
    for (int i = threadIdx.x; i < NB; i += blockDim.x) hist[i] = 0;
    __syncthreads();
    const int chunk = (E + NB - 1) / NB;   // 2046 -> <=8 edges/thread
    int e0 = blockIdx.x * chunk;
    int e1 = e0 + chunk; if (e1 > E) e1 = E;
    unsigned su[8]; unsigned char dlv[8]; short bv[8];
#pragma unroll
    for (int j = 0; j < 8; ++j) {
        int e = e0 + threadIdx.x + j * 256;
        if (e < e1) {
            int d = dst[e];
            int b = d >> BSHIFT;
            __half uh = __float2half_rn(attr[e]);
            su[j]  = ((unsigned)src[e] << 16) | (unsigned)__half_as_ushort(uh);
            dlv[j] = (unsigned char)(d & (BSIZE - 1));
            bv[j]  = (short)b;
            atomicAdd(&hist[b], 1);
        }
    }
    __syncthreads();
    for (int i = threadIdx.x; i < NB; i += blockDim.x) {
        int cnt = hist[i];
        base[i] = cnt ? atomicAdd(&bcursor[i], cnt) : 0;
        hist[i] = 0;
    }
    __syncthreads();
#pragma unroll
    for (int j = 0; j < 8; ++j) {
        int e = e0 + threadIdx.x + j * 256;
        if (e < e1) {
            int b = bv[j];
            int slot = base[b] + atomicAdd(&hist[b], 1);
            es1su[slot] = su[j];
            es1dl[slot] = dlv[j];
        }
    }
}

// ---------------- exact placement within bucket + {beg,end}; packs {src, half2(1-u,u)} ----------------
__global__ __launch_bounds__(256) void placeC_kernel(const int* __restrict__ bcursor,
                                                     const unsigned* __restrict__ es1su,
                                                     const unsigned char* __restrict__ es1dl,
                                                     int2* __restrict__ rowrange,
                                                     uint2* __restrict__ es8) {
    __shared__ int hist[BSIZE];
    __shared__ int stmp[BSIZE];
    __shared__ int cur[BSIZE];
    int b = blockIdx.x;
    int t = threadIdx.x;
    int bs = b * CAP;
    int be = bcursor[b];
    if (t < BSIZE) hist[t] = 0;
    __syncthreads();
    unsigned su[10]; unsigned char dlv[10];
#pragma unroll
    for (int j = 0; j < 10; ++j) {
        int i = bs + t + j * 256;
        if (i < be) {
            su[j]  = es1su[i];
            dlv[j] = es1dl[i];
            atomicAdd(&hist[dlv[j]], 1);
        }
    }
    __syncthreads();
    if (t < BSIZE) {
        int v = hist[t];
        int incl = v;
#pragma unroll
        for (int o = 1; o < 64; o <<= 1) {
            int nv = __shfl_up(incl, o, 64);
            if ((t & 63) >= o) incl += nv;
        }
        stmp[t] = incl;
    }
    __syncthreads();
    if (t < BSIZE) {
        int excl = stmp[t] - hist[t] + ((t >= 64) ? stmp[63] : 0);
        cur[t] = excl;
        int node = b * BSIZE + t;
        if (node < NN) {
            int2 rr; rr.x = bs + excl; rr.y = bs + excl + hist[t];
            rowrange[node] = rr;
        }
    }
    __syncthreads();
#pragma unroll
    for (int j = 0; j < 10; ++j) {
        int i = bs + t + j * 256;
        if (i < be) {
            unsigned r = su[j];
            int dl = dlv[j];
            int slot = bs + atomicAdd(&cur[dl], 1);
            __half uh = __ushort_as_half((unsigned short)(r & 0xffffu));
            __half2 p = __halves2half2(__hsub(__ushort_as_half((unsigned short)0x3C00u), uh), uh);
            uint2 rec;
            rec.x = r >> 16;
            rec.y = *reinterpret_cast<unsigned*>(&p);
            es8[slot] = rec;
        }
    }
}

// ---------------- gather raw features, CIN=32 (layer 0): one wave/node, 2 edges/iter ----------------
// S row (64 halves) = interleaved {s0[c], s1[c]} half2, deg-normalized.
__global__ __launch_bounds__(256) void gatherS32_kernel(const int2* __restrict__ rowrange,
                                                        const uint2* __restrict__ es8,
                                                        const __half* __restrict__ xh,
                                                        __half* __restrict__ S, int n_nodes) {
    int n = (blockIdx.x * blockDim.x + threadIdx.x) >> 6;
    int lane = threadIdx.x & 63;
    if (n >= n_nodes) return;
    int2 rr = rowrange[n];
    int beg = __builtin_amdgcn_readfirstlane(rr.x);
    int end = __builtin_amdgcn_readfirstlane(rr.y);
    int c = lane & 31;
    const __half* xb = xh + c;
    float a0 = 0.f, a1 = 0.f, a2 = 0.f, a3 = 0.f;
    float b0 = 0.f, b1 = 0.f, b2 = 0.f, b3 = 0.f;
    int i = beg + (lane >> 5);          // half-wave h handles edges beg+h, beg+h+2, ...
    for (; i + 6 < end; i += 8) {       // 4 edges per half-wave, 8 per wave
        uint2 q0 = es8[i];
        uint2 q1 = es8[i + 2];
        uint2 q2 = es8[i + 4];
        uint2 q3 = es8[i + 6];
        float x0 = __half2float(xb[(size_t)q0.x << 5]);
        float x1 = __half2float(xb[(size_t)q1.x << 5]);
        float x2 = __half2float(xb[(size_t)q2.x << 5]);
        float x3 = __half2float(xb[(size_t)q3.x << 5]);
        __half2 u0 = __builtin_bit_cast(__half2, q0.y);
        __half2 u1 = __builtin_bit_cast(__half2, q1.y);
        __half2 u2 = __builtin_bit_cast(__half2, q2.y);
        __half2 u3 = __builtin_bit_cast(__half2, q3.y);
        a0 = fmaf(__low2float(u0), x0, a0); b0 = fmaf(__high2float(u0), x0, b0);
        a1 = fmaf(__low2float(u1), x1, a1); b1 = fmaf(__high2float(u1), x1, b1);
        a2 = fmaf(__low2float(u2), x2, a2); b2 = fmaf(__high2float(u2), x2, b2);
        a3 = fmaf(__low2float(u3), x3, a3); b3 = fmaf(__high2float(u3), x3, b3);
    }
    for (; i < end; i += 2) {
        uint2 q = es8[i];
        float xv = __half2float(xb[(size_t)q.x << 5]);
        __half2 u = __builtin_bit_cast(__half2, q.y);
        a0 = fmaf(__low2float(u), xv, a0); b0 = fmaf(__high2float(u), xv, b0);
    }
    float a = (a0 + a1) + (a2 + a3);
    float b = (b0 + b1) + (b2 + b3);
    a += __shfl_xor(a, 32);
    b += __shfl_xor(b, 32);
    float degv = (float)(end - beg);
    if (degv < 1.f) degv = 1.f;
    float inv = 1.f / degv;
    if (lane < 32) {
        reinterpret_cast<__half2*>(S + (size_t)n * 64)[c] = __floats2half2_rn(a * inv, b * inv);
    }
}

// ---------------- gather raw features, CIN=64 (layer 1): one wave/node, lane=channel ----------------
__global__ __launch_bounds__(256) void gatherS64_kernel(const int2* __restrict__ rowrange,
                                                        const uint2* __restrict__ es8,
                                                        const __half* __restrict__ ht,
                                                        __half* __restrict__ S, int n_nodes) {
    int n = (blockIdx.x * blockDim.x + threadIdx.x) >> 6;
    int lane = threadIdx.x & 63;
    if (n >= n_nodes) return;
    int2 rr = rowrange[n];
    int beg = __builtin_amdgcn_readfirstlane(rr.x);
    int end = __builtin_amdgcn_readfirstlane(rr.y);
    const __half* xb = ht + lane;
    float a0 = 0.f, a1 = 0.f, a2 = 0.f, a3 = 0.f;
    float b0 = 0.f, b1 = 0.f, b2 = 0.f, b3 = 0.f;
    int i = beg;
    if (i < end && (i & 1)) {           // peel to 16B alignment of es8+i
        uint2 q = es8[i];
        float xv = __half2float(xb[(size_t)q.x << 6]);
        __half2 u = __builtin_bit_cast(__half2, q.y);
        a0 = fmaf(__low2float(u), xv, a0); b0 = fmaf(__high2float(u), xv, b0);
        ++i;
    }
    for (; i + 7 < end; i += 8) {       // 8 table loads in flight
        uint4 p0 = *reinterpret_cast<const uint4*>(es8 + i);
        uint4 p1 = *reinterpret_cast<const uint4*>(es8 + i + 2);
        uint4 p2 = *reinterpret_cast<const uint4*>(es8 + i + 4);
        uint4 p3 = *reinterpret_cast<const uint4*>(es8 + i + 6);
        float x0 = __half2float(xb[(size_t)p0.x << 6]);
        float x1 = __half2float(xb[(size_t)p0.z << 6]);
        float x2 = __half2float(xb[(size_t)p1.x << 6]);
        float x3 = __half2float(xb[(size_t)p1.z << 6]);
        float x4 = __half2float(xb[(size_t)p2.x << 6]);
        float x5 = __half2float(xb[(size_t)p2.z << 6]);
        float x6 = __half2float(xb[(size_t)p3.x << 6]);
        float x7 = __half2float(xb[(size_t)p3.z << 6]);
        __half2 u0 = __builtin_bit_cast(__half2, p0.y);
        __half2 u1 = __builtin_bit_cast(__half2, p0.w);
        __half2 u2 = __builtin_bit_cast(__half2, p1.y);
        __half2 u3 = __builtin_bit_cast(__half2, p1.w);
        __half2 u4 = __builtin_bit_cast(__half2, p2.y);
        __half2 u5 = __builtin_bit_cast(__half2, p2.w);
        __half2 u6 = __builtin_bit_cast(__half2, p3.y);
        __half2 u7 = __builtin_bit_cast(__half2, p3.w);
        a0 = fmaf(__low2float(u0), x0, a0); b0 = fmaf(__high2float(u0), x0, b0);
        a1 = fmaf(__low2float(u1), x1, a1); b1 = fmaf(__high2float(u1), x1, b1);
        a2 = fmaf(__low2float(u2), x2, a2); b2 = fmaf(__high2float(u2), x2, b2);
        a3 = fmaf(__low2float(u3), x3, a3); b3 = fmaf(__high2float(u3), x3, b3);
        a0 = fmaf(__low2float(u4), x4, a0); b0 = fmaf(__high2float(u4), x4, b0);
        a1 = fmaf(__low2float(u5), x5, a1); b1 = fmaf(__high2float(u5), x5, b1);
        a2 = fmaf(__low2float(u6), x6, a2); b2 = fmaf(__high2float(u6), x6, b2);
        a3 = fmaf(__low2float(u7), x7, a3); b3 = fmaf(__high2float(u7), x7, b3);
    }
    for (; i + 1 < end; i += 2) {
        uint4 p = *reinterpret_cast<const uint4*>(es8 + i);
        float x0 = __half2float(xb[(size_t)p.x << 6]);
        float x1 = __half2float(xb[(size_t)p.z << 6]);
        __half2 u0 = __builtin_bit_cast(__half2, p.y);
        __half2 u1 = __builtin_bit_cast(__half2, p.w);
        a0 = fmaf(__low2float(u0), x0, a0); b0 = fmaf(__high2float(u0), x0, b0);
        a1 = fmaf(__low2float(u1), x1, a1); b1 = fmaf(__high2float(u1), x1, b1);
    }
    if (i < end) {
        uint2 q = es8[i];
        float xv = __half2float(xb[(size_t)q.x << 6]);
        __half2 u = __builtin_bit_cast(__half2, q.y);
        a0 = fmaf(__low2float(u), xv, a0); b0 = fmaf(__high2float(u), xv, b0);
    }
    float a = (a0 + a1) + (a2 + a3);
    float b = (b0 + b1) + (b2 + b3);
    float degv = (float)(end - beg);
    if (degv < 1.f) degv = 1.f;
    float inv = 1.f / degv;
    reinterpret_cast<__half2*>(S + (size_t)n * 128)[lane] = __floats2half2_rn(a * inv, b * inv);
}

// ---------------- layer-0 post-GEMM: h = elu(bn(A @ Bcat)), A=[s0⋈s1 | x], K=96, N=64 ----------------
__global__ __launch_bounds__(256) void gemmL0_kernel(const __half* __restrict__ S,
                                                     const __half* __restrict__ xh,
                                                     const __half* __restrict__ Bf0,
                                                     const float* __restrict__ bn,
                                                     __half* __restrict__ hout, int n_nodes) {
    const int lane = threadIdx.x & 63;
    const int wid  = threadIdx.x >> 6;
    int m0 = (blockIdx.x * 4 + wid) * 16;
    if (m0 >= n_nodes) return;
    f32x4 acc[4];
#pragma unroll
    for (int i = 0; i < 4; ++i) acc[i] = (f32x4){0.f, 0.f, 0.f, 0.f};
    const int arow = m0 + (lane & 15);
    const int koff = ((lane >> 4) << 3);
    const f16x8* bf = reinterpret_cast<const f16x8*>(Bf0);
    const _Float16* sp = (const _Float16*)S  + (size_t)arow * 64 + koff;
    const _Float16* xp = (const _Float16*)xh + (size_t)arow * 32 + koff;
    f16x8 a0 = *reinterpret_cast<const f16x8*>(sp);
    f16x8 a1 = *reinterpret_cast<const f16x8*>(sp + 32);
    f16x8 a2 = *reinterpret_cast<const f16x8*>(xp);
#pragma unroll
    for (int nt = 0; nt < 4; ++nt)
        acc[nt] = __builtin_amdgcn_mfma_f32_16x16x32_f16(a0, bf[nt * 64 + lane], acc[nt], 0, 0, 0);
#pragma unroll
    for (int nt = 0; nt < 4; ++nt)
        acc[nt] = __builtin_amdgcn_mfma_f32_16x16x32_f16(a1, bf[(4 + nt) * 64 + lane], acc[nt], 0, 0, 0);
#pragma unroll
    for (int nt = 0; nt < 4; ++nt)
        acc[nt] = __builtin_amdgcn_mfma_f32_16x16x32_f16(a2, bf[(8 + nt) * 64 + lane], acc[nt], 0, 0, 0);
    const int c_lo  = lane & 15;
    const int rbase = ((lane >> 4) << 2);
#pragma unroll
    for (int nt = 0; nt < 4; ++nt) {
        int cc = nt * 16 + c_lo;
        float sc = bn[cc], sh = bn[64 + cc];
#pragma unroll
        for (int r = 0; r < 4; ++r) {
            int row = m0 + rbase + r;
            float v = acc[nt][r] * sc + sh;
            v = v > 0.f ? v : expm1f(v);
            hout[(size_t)row * 64 + cc] = __float2half(v);
        }
    }
}

// ---------------- layer-1 post-GEMM: A=[s0⋈s1 (128) | h (64)], K=192, N=64 ----------------
__global__ __launch_bounds__(256) void gemmL1_kernel(const __half* __restrict__ S,
                                                     const __half* __restrict__ hin,
                                                     const __half* __restrict__ Bf1,
                                                     const float* __restrict__ bn,
                                                     __half* __restrict__ hout, int n_nodes) {
    const int lane = threadIdx.x & 63;
    const int wid  = threadIdx.x >> 6;
    int m0 = (blockIdx.x * 4 + wid) * 16;
    if (m0 >= n_nodes) return;
    f32x4 acc[4];
#pragma unroll
    for (int i = 0; i < 4; ++i) acc[i] = (f32x4){0.f, 0.f, 0.f, 0.f};
    const int arow = m0 + (lane & 15);
    const int koff = ((lane >> 4) << 3);
    const f16x8* bf = reinterpret_cast<const f16x8*>(Bf1);
    const _Float16* sp = (const _Float16*)S   + (size_t)arow * 128 + koff;
    const _Float16* hp = (const _Float16*)hin + (size_t)arow * 64  + koff;
#pragma unroll
    for (int ks = 0; ks < 6; ++ks) {
        f16x8 av = (ks < 4) ? *reinterpret_cast<const f16x8*>(sp + ks * 32)
                            : *reinterpret_cast<const f16x8*>(hp + (ks - 4) * 32);
#pragma unroll
        for (int nt = 0; nt < 4; ++nt)
            acc[nt] = __builtin_amdgcn_mfma_f32_16x16x32_f16(av, bf[(ks * 4 + nt) * 64 + lane], acc[nt], 0, 0, 0);
    }
    const int c_lo  = lane & 15;
    const int rbase = ((lane >> 4) << 2);
#pragma unroll
    for (int nt = 0; nt < 4; ++nt) {
        int cc = nt * 16 + c_lo;
        float sc = bn[cc], sh = bn[64 + cc];
#pragma unroll
        for (int r = 0; r < 4; ++r) {
            int row = m0 + rbase + r;
            float v = acc[nt][r] * sc + sh;
            v = v > 0.f ? v : expm1f(v);
            hout[(size_t)row * 64 + cc] = __float2half(v);
        }
    }
}

// ---------------- layer-2 MFMA GEMM: [a|b packed, z] from h (fp16), K=64 (unchanged) ----------------
__global__ __launch_bounds__(256) void gemm7_kernel(const __half* __restrict__ h,
                               const __half* __restrict__ Bf7,
                               const float* __restrict__ Bb,    // (7)
                               __half* __restrict__ Yab7H,      // (n,7,2) halves
                               float* __restrict__ Z7,          // (n,7)
                               int n_nodes) {
    const int lane = threadIdx.x & 63;
    const int wid  = threadIdx.x >> 6;
    int m0 = (blockIdx.x * 4 + wid) * 16;
    if (m0 >= n_nodes) return;

    f32x4 acc[2];
    acc[0] = (f32x4){0.f, 0.f, 0.f, 0.f};
    acc[1] = (f32x4){0.f, 0.f, 0.f, 0.f};
    const int arow = m0 + (lane & 15);
    const int koff = ((lane >> 4) << 3);
    const f16x8* bf = reinterpret_cast<const f16x8*>(Bf7);
#pragma unroll
    for (int ks = 0; ks < 2; ++ks) {
        f16x8 av = *reinterpret_cast<const f16x8*>(
            (const _Float16*)h + (size_t)arow * 64 + ks * 32 + koff);
#pragma unroll
        for (int nt = 0; nt < 2; ++nt) {
            f16x8 bv = bf[(ks * 2 + nt) * 64 + lane];
            acc[nt] = __builtin_amdgcn_mfma_f32_16x16x32_f16(av, bv, acc[nt], 0, 0, 0);
        }
    }
    const int c_lo  = lane & 15;
    const int rbase = ((lane >> 4) << 2);
#pragma unroll
    for (int r = 0; r < 4; ++r) {
        int row = m0 + rbase + r;
        if (c_lo < 7) {
            Yab7H[(size_t)row * 14 + 2 * c_lo] = __float2half(acc[0][r]);
            Z7[(size_t)row * 7 + c_lo] = acc[1][r] + Bb[c_lo];
        } else if (c_lo >= 8 && c_lo < 15) {
            Yab7H[(size_t)row * 14 + 2 * (c_lo - 8) + 1] = __float2half(acc[0][r]);
        }
    }
}

// ---------------- gather (C=7) + log_softmax fused: 8 lanes per node (unchanged) ----------------
__global__ void gather7_final_kernel(const int2* __restrict__ rowrange,
                                     const uint2* __restrict__ es8,
                                     const __half2* __restrict__ Yab7H,  // (n,7) half2{a,b}
                                     const float* __restrict__ Z7,
                                     float* __restrict__ out, int n_nodes) {
    int t = blockIdx.x * blockDim.x + threadIdx.x;
    int n = t >> 3;
    int c = t & 7;
    if (n >= n_nodes) return;
    int2 rr = rowrange[n];
    int beg = rr.x, end = rr.y;
    float acc0 = 0.f, acc1 = 0.f, acc2 = 0.f, acc3 = 0.f;
    if (c < 7) {
        int i = beg;
        for (; i + 3 < end; i += 4) {
            uint2 q0 = es8[i];
            uint2 q1 = es8[i + 1];
            uint2 q2 = es8[i + 2];
            uint2 q3 = es8[i + 3];
            __half2 v0 = Yab7H[(size_t)q0.x * 7 + c];
            __half2 v1 = Yab7H[(size_t)q1.x * 7 + c];
            __half2 v2 = Yab7H[(size_t)q2.x * 7 + c];
            __half2 v3 = Yab7H[(size_t)q3.x * 7 + c];
            acc0 = __builtin_amdgcn_fdot2(__builtin_bit_cast(h2f, v0), __builtin_bit_cast(h2f, q0.y), acc0, false);
            acc1 = __builtin_amdgcn_fdot2(__builtin_bit_cast(h2f, v1), __builtin_bit_cast(h2f, q1.y), acc1, false);
            acc2 = __builtin_amdgcn_fdot2(__builtin_bit_cast(h2f, v2), __builtin_bit_cast(h2f, q2.y), acc2, false);
            acc3 = __builtin_amdgcn_fdot2(__builtin_bit_cast(h2f, v3), __builtin_bit_cast(h2f, q3.y), acc3, false);
        }
        for (; i < end; ++i) {
            uint2 q = es8[i];
            __half2 v = Yab7H[(size_t)q.x * 7 + c];
            acc0 = __builtin_amdgcn_fdot2(__builtin_bit_cast(h2f, v), __builtin_bit_cast(h2f, q.y), acc0, false);
        }
    }
    float acc = (acc0 + acc1) + (acc2 + acc3);
    float degv = (float)(end - beg);
    if (degv < 1.f) degv = 1.f;
    float v = (c < 7) ? (acc / degv + Z7[n * 7 + c]) : -1e30f;
    float m = v;
#pragma unroll
    for (int o = 1; o < 8; o <<= 1) m = fmaxf(m, __shfl_xor(m, o, 8));
    float ex = (c < 7) ? expf(v - m) : 0.f;
    float ssum = ex;
#pragma unroll
    for (int o = 1; o < 8; o <<= 1) ssum += __shfl_xor(ssum, o, 8);
    if (c < 7) out[n * 7 + c] = v - m - logf(ssum);
}

extern "C" void kernel_launch(void* const* d_in, const int* in_sizes, int n_in,
                              void* d_out, int out_size, void* d_ws, size_t ws_size,
                              hipStream_t stream) {
    const float* x    = (const float*)d_in[0];
    const int*   ei   = (const int*)d_in[1];
    const float* attr = (const float*)d_in[2];
    const float* W0 = (const float*)d_in[3];
    const float* R0 = (const float*)d_in[4];
    const float* B0 = (const float*)d_in[5];
    const float* W1 = (const float*)d_in[6];
    const float* R1 = (const float*)d_in[7];
    const float* B1 = (const float*)d_in[8];
    const float* W2 = (const float*)d_in[9];
    const float* R2 = (const float*)d_in[10];
    const float* B2 = (const float*)d_in[11];
    const float* G0  = (const float*)d_in[12];
    const float* BE0 = (const float*)d_in[13];
    const float* RM0 = (const float*)d_in[14];
    const float* RV0 = (const float*)d_in[15];
    const float* G1  = (const float*)d_in[16];
    const float* BE1 = (const float*)d_in[17];
    const float* RM1 = (const float*)d_in[18];
    const float* RV1 = (const float*)d_in[19];

    const int* src = ei;
    const int* dst = ei + NE;
    float* out = (float*)d_out;

    // workspace layout
    char* ws = (char*)d_ws;
    size_t off = 0;
    auto alloc = [&](size_t bytes) { char* p = ws + off; off += (bytes + 255) & ~size_t(255); return p; };
    int*           bcursor  = (int*)          alloc(NB * sizeof(int));
    int2*          rowrange = (int2*)         alloc((size_t)NN * sizeof(int2));
    unsigned*      es1su    = (unsigned*)     alloc((size_t)NB * CAP * sizeof(unsigned));
    unsigned char* es1dl    = (unsigned char*)alloc((size_t)NB * CAP * sizeof(unsigned char));
    uint2*         es8      = (uint2*)        alloc((size_t)NB * CAP * sizeof(uint2));
    __half*        Bf0      = (__half*)       alloc((size_t)12 * 64 * 8 * sizeof(__half));
    __half*        Bf1      = (__half*)       alloc((size_t)24 * 64 * 8 * sizeof(__half));
    __half*        Bf7      = (__half*)       alloc((size_t)4 * 64 * 8 * sizeof(__half));
    float*         bn0      = (float*)        alloc(128 * sizeof(float));
    float*         bn1      = (float*)        alloc(128 * sizeof(float));
    __half*        xh       = (__half*)       alloc((size_t)NN * 32 * sizeof(__half));
    __half*        S        = (__half*)       alloc((size_t)NN * 128 * sizeof(__half));
    __half*        h0       = (__half*)       alloc((size_t)NN * 64 * sizeof(__half));
    __half*        h1       = (__half*)       alloc((size_t)NN * 64 * sizeof(__half));
    __half*        Yab7H    = (__half*)       alloc((size_t)NN * 14 * sizeof(__half));
    float*         Z7       = (float*)        alloc((size_t)NN * 7 * sizeof(float));

    const int B = 256;
    const int gM    = ((NN + 15) / 16 + 3) / 4;          // 782: 16-row M-tiles, 4 waves/block
    const int gGath = (NN * 64) / (B);                   // 12500: 1 wave/node
    const int gN8   = (NN * 8 + B - 1) / B;              // 1563
    const int gConv = ((NN * 32 / 8) + B - 1) / B;       // 782: x->half, 8 floats/thread
    const int gPrep = 42 + (NB + 63) / 64;               // 49

    // ---- setup: weight prep (interleaved cat) + BN fold + cursor init ----
    prep_all_kernel<<<gPrep, 64, 0, stream>>>(W0, R0, W1, R1, W2, R2, B0, B1,
                                              G0, BE0, RM0, RV0, G1, BE1, RM1, RV1,
                                              Bf0, Bf1, Bf7, bn0, bn1, bcursor);

    // ---- binB (CSR binning) co-launched with x->half conversion (independent) ----
    binB_xh_kernel<<<NB + gConv, B, 0, stream>>>(src, dst, attr, bcursor, es1su, es1dl, NE, x, xh);

    // ---- exact placement -> es8, rowrange ----
    placeC_kernel<<<NB, B, 0, stream>>>(bcursor, es1su, es1dl, rowrange, es8);

    // ---- layer 0: aggregate raw x, then GEMM(K=96)+BN+ELU ----
    gatherS32_kernel<<<gGath, B, 0, stream>>>(rowrange, es8, xh, S, NN);
    gemmL0_kernel<<<gM, B, 0, stream>>>(S, xh, Bf0, bn0, h0, NN);

    // ---- layer 1: aggregate raw h0, then GEMM(K=192)+BN+ELU ----
    gatherS64_kernel<<<gGath, B, 0, stream>>>(rowrange, es8, h0, S, NN);
    gemmL1_kernel<<<gM, B, 0, stream>>>(S, h0, Bf1, bn1, h1, NN);

    // ---- layer 2: H=64 -> C=7 transform-then-gather (COUT small), log_softmax ----
    gemm7_kernel<<<gM, B, 0, stream>>>(h1, Bf7, B2, Yab7H, Z7, NN);
    gather7_final_kernel<<<gN8, B, 0, stream>>>(rowrange, es8, (const __half2*)Yab7H, Z7, out, NN);
}